// Round 5
// baseline (1780.628 us; speedup 1.0000x reference)
//
#include <hip/hip_runtime.h>
#include <hip/hip_bf16.h>
#include <math.h>
#include <stdint.h>

// Problem constants (fixed by setup_inputs)
#define D_DIM 1024
#define T_DIM 4096
#define B_DIM 16
#define C_DIM 1024              // T/RATE, RATE=4
#define NCHUNK (B_DIM * C_DIM)  // 16384
#define NKT 32                  // D/32 k-tiles
#define TPAIR (T_DIM/2)         // 2048 t-pair rows per (b,kt)
#define EPAIR (D_DIM/2)         // 512 e-pair rows per kt
#define TAU_INV 10.0f
#define ALPHA 0.7f
#define LN_EPS 1e-5f
#define XSCALE 4.0f
#define WSCALE 32.0f
#define INV_SCALE (1.0f/128.0f)

typedef _Float16 h8 __attribute__((ext_vector_type(8)));
typedef float f4 __attribute__((ext_vector_type(4)));

static __device__ __forceinline__ void gload16(const void* g, void* s) {
    __builtin_amdgcn_global_load_lds(
        (const __attribute__((address_space(1))) unsigned int*)g,
        (__attribute__((address_space(3))) unsigned int*)s, 16, 0, 0);
}

// ---------------------------------------------------------------------------
// Pre-pass X: fp32 [B][D][T] -> split-fp16 hi/lo, transposed+swizzled layout:
// element hi(x[b][d][t]*4) at row tp=t>>1 (within (b,kt)), slot
// sigma = ((t&1)*4 + (d>>3)%4) ^ (tp&7), half j = d&7. Rows are 128B; a
// [128t x 32d] GEMM tile is a CONTIGUOUS 8KB region -> global_load_lds direct.
// FUSED: also accumulates tokN2[b][t] += sum_d x^2 (4-way atomic partials).
// ---------------------------------------------------------------------------
__global__ __launch_bounds__(256)
void split_x_kernel(const float* __restrict__ x, uint4* __restrict__ Xh,
                    uint4* __restrict__ Xl, float* __restrict__ tokN2)
{
    const int tid = threadIdx.x;
    const int t1 = blockIdx.x * 256;
    const int kt = blockIdx.y;
    const int b  = blockIdx.z;
    const int d0 = kt * 32;
    __shared__ __align__(16) float xs[32][264];
    const float* X = x + ((size_t)b * D_DIM + d0) * T_DIM + t1;
    #pragma unroll
    for (int i = 0; i < 8; i++) {
        int idx = tid + i * 256;
        int d = idx >> 6, tq = idx & 63;
        *(float4*)&xs[d][tq * 4] = *(const float4*)(X + (size_t)d * T_DIM + tq * 4);
    }
    __syncthreads();
    const size_t rowbase = (size_t)(b * NKT + kt) * TPAIR + (t1 >> 1);
    #pragma unroll
    for (int ch = 0; ch < 4; ch++) {
        int tp_l = ch * 32 + (tid >> 3);
        int sg = tid & 7;
        int pg = sg ^ (tp_l & 7);
        int p = pg >> 2, g = pg & 3;
        int tl = tp_l * 2 + p;
        unsigned hb[8], lb[8];
        float n2 = 0.f;
        #pragma unroll
        for (int j = 0; j < 8; j++) {
            float raw = xs[g * 8 + j][tl];
            n2 = fmaf(raw, raw, n2);
            float v = raw * XSCALE;
            _Float16 hv = (_Float16)v;
            float hf = (float)hv;
            _Float16 lv = (_Float16)(v - hf);
            hb[j] = (unsigned)__builtin_bit_cast(unsigned short, hv);
            lb[j] = (unsigned)__builtin_bit_cast(unsigned short, lv);
        }
        uint4 uh, ul;
        uh.x = hb[0] | (hb[1] << 16); uh.y = hb[2] | (hb[3] << 16);
        uh.z = hb[4] | (hb[5] << 16); uh.w = hb[6] | (hb[7] << 16);
        ul.x = lb[0] | (lb[1] << 16); ul.y = lb[2] | (lb[3] << 16);
        ul.z = lb[4] | (lb[5] << 16); ul.w = lb[6] | (lb[7] << 16);
        size_t si = (rowbase + tp_l) * 8 + sg;
        Xh[si] = uh; Xl[si] = ul;
        atomicAdd(&tokN2[b * T_DIM + t1 + tl], n2);
    }
}

// ---------------------------------------------------------------------------
// Pre-pass W: [e][d] fp32 -> split-fp16 hi/lo, same paired-row swizzled layout
// over (kt, e-pair). W scaled by 32.
// ---------------------------------------------------------------------------
__global__ __launch_bounds__(256)
void split_w_kernel(const float* __restrict__ W, uint4* __restrict__ Wh,
                    uint4* __restrict__ Wl)
{
    const int tid = threadIdx.x;
    const int e1 = blockIdx.x * 256;
    const int kt = blockIdx.y;
    const int d0 = kt * 32;
    const size_t rowbase = (size_t)kt * EPAIR + (e1 >> 1);
    #pragma unroll
    for (int ch = 0; ch < 4; ch++) {
        int ep_l = ch * 32 + (tid >> 3);
        int sg = tid & 7;
        int pg = sg ^ (ep_l & 7);
        int p = pg >> 2, g = pg & 3;
        int e = e1 + ep_l * 2 + p;
        const float* src = W + (size_t)e * D_DIM + d0 + g * 8;
        float4 a = *(const float4*)src;
        float4 c = *(const float4*)(src + 4);
        float vv[8] = {a.x, a.y, a.z, a.w, c.x, c.y, c.z, c.w};
        unsigned hb[8], lb[8];
        #pragma unroll
        for (int j = 0; j < 8; j++) {
            float v = vv[j] * WSCALE;
            _Float16 hv = (_Float16)v;
            float hf = (float)hv;
            _Float16 lv = (_Float16)(v - hf);
            hb[j] = (unsigned)__builtin_bit_cast(unsigned short, hv);
            lb[j] = (unsigned)__builtin_bit_cast(unsigned short, lv);
        }
        uint4 uh, ul;
        uh.x = hb[0] | (hb[1] << 16); uh.y = hb[2] | (hb[3] << 16);
        uh.z = hb[4] | (hb[5] << 16); uh.w = hb[6] | (hb[7] << 16);
        ul.x = lb[0] | (lb[1] << 16); ul.y = lb[2] | (lb[3] << 16);
        ul.z = lb[4] | (lb[5] << 16); ul.w = lb[6] | (lb[7] << 16);
        size_t si = (rowbase + ep_l) * 8 + sg;
        Wh[si] = uh; Wl[si] = ul;
    }
}

// ---------------------------------------------------------------------------
// MFMA GEMM: feat[t][e] = sum_d x*W (split-fp16 x3), 128x128 tile, BK=32,
// 4 waves (each 64x64 out). 2-phase double-buffered pipeline (T3 recipe):
// STAGE(next) issued before compute(cur); one raw s_barrier + counted
// vmcnt drain per K-step (loads fly under ds_read+MFMA). Fused epilogue.
// ---------------------------------------------------------------------------
__global__ __launch_bounds__(256, 2)
void gemm_mfma_kernel(const uint4* __restrict__ Xh, const uint4* __restrict__ Xl,
                      const uint4* __restrict__ Wh, const uint4* __restrict__ Wl,
                      const float* __restrict__ b_proj, const float* __restrict__ ln_g,
                      const float* __restrict__ w_score, float* __restrict__ scal)
{
    const int tid = threadIdx.x;
    const int l   = tid & 63;
    const int wid = tid >> 6;
    const int wm  = wid >> 1, we = wid & 1;

    // XCD-chunked swizzle: XCD x gets panels [x*64, x*64+64); 8 e-blocks of a
    // panel are adjacent ids on the same XCD -> X tiles served from its L2.
    int sid = blockIdx.x;
    int xcd = sid & 7, jj = sid >> 3;
    int panel = xcd * 64 + (jj >> 3);
    int eblk  = jj & 7;
    int b = panel >> 5, tblk = panel & 31;
    const int t0 = tblk * 128, e0 = eblk * 128;

    // double-buffered: buf parity p at offset p*32768; within a buffer:
    // [0]=Xh [8192]=Xl [16384]=Wh [24576]=Wl
    __shared__ __align__(16) char lds[65536];

    const int h    = (l & 15) >> 1;
    const int slot = (((l & 1) << 2) | (l >> 4)) ^ h;
    const int aoff = (wm * 32 + h) * 128 + slot * 16;
    const int boff = (we * 32 + h) * 128 + slot * 16;

    f4 acc[4][4];
    #pragma unroll
    for (int mi = 0; mi < 4; mi++)
        #pragma unroll
        for (int ni = 0; ni < 4; ni++) acc[mi][ni] = (f4){0.f, 0.f, 0.f, 0.f};

    const char* gXh0 = (const char*)Xh + ((size_t)b * NKT * TPAIR + (size_t)(t0 >> 1)) * 128;
    const char* gXl0 = (const char*)Xl + ((size_t)b * NKT * TPAIR + (size_t)(t0 >> 1)) * 128;
    const char* gWh0 = (const char*)Wh + (size_t)(e0 >> 1) * 128;
    const char* gWl0 = (const char*)Wl + (size_t)(e0 >> 1) * 128;

    const int stg = wid * 2048;       // this wave's 2KB of each 8KB buffer
    const int lo16 = l * 16;

    auto stage = [&](int off, int kt) {
        const char* pxh = gXh0 + (size_t)kt * (TPAIR * 128);
        const char* pxl = gXl0 + (size_t)kt * (TPAIR * 128);
        const char* pwh = gWh0 + (size_t)kt * (EPAIR * 128);
        const char* pwl = gWl0 + (size_t)kt * (EPAIR * 128);
        char* base = lds + off;
        gload16(pxh + stg + lo16,        base + stg);
        gload16(pxh + stg + 1024 + lo16, base + stg + 1024);
        gload16(pxl + stg + lo16,        base + 8192 + stg);
        gload16(pxl + stg + 1024 + lo16, base + 8192 + stg + 1024);
        gload16(pwh + stg + lo16,        base + 16384 + stg);
        gload16(pwh + stg + 1024 + lo16, base + 16384 + stg + 1024);
        gload16(pwl + stg + lo16,        base + 24576 + stg);
        gload16(pwl + stg + 1024 + lo16, base + 24576 + stg + 1024);
    };
    auto compute = [&](int off) {
        const char* base = lds + off;
        h8 ah[4], al[4], bh[4], bl[4];
        #pragma unroll
        for (int mi = 0; mi < 4; mi++) {
            ah[mi] = *(const h8*)(base + aoff + mi * 1024);
            al[mi] = *(const h8*)(base + 8192 + aoff + mi * 1024);
        }
        #pragma unroll
        for (int ni = 0; ni < 4; ni++) {
            bh[ni] = *(const h8*)(base + 16384 + boff + ni * 1024);
            bl[ni] = *(const h8*)(base + 24576 + boff + ni * 1024);
        }
        #pragma unroll
        for (int mi = 0; mi < 4; mi++)
            #pragma unroll
            for (int ni = 0; ni < 4; ni++) {
                acc[mi][ni] = __builtin_amdgcn_mfma_f32_16x16x32_f16(ah[mi], bh[ni], acc[mi][ni], 0, 0, 0);
                acc[mi][ni] = __builtin_amdgcn_mfma_f32_16x16x32_f16(ah[mi], bl[ni], acc[mi][ni], 0, 0, 0);
                acc[mi][ni] = __builtin_amdgcn_mfma_f32_16x16x32_f16(al[mi], bh[ni], acc[mi][ni], 0, 0, 0);
            }
    };

    // prologue: fill buf0 with kt=0
    stage(0, 0);
    asm volatile("s_waitcnt vmcnt(0)" ::: "memory");
    __builtin_amdgcn_s_barrier();

    int off = 0;
    #pragma unroll 1
    for (int kt = 0; kt < NKT - 1; kt++) {
        stage(off ^ 32768, kt + 1);   // next tile's loads fly under compute
        compute(off);
        asm volatile("s_waitcnt vmcnt(0)" ::: "memory");  // next tile landed
        __builtin_amdgcn_s_barrier();                     // + all reads done
        off ^= 32768;
    }
    compute(off);                     // kt = 31, already resident

    // Epilogue: C/D layout col=lane&15 (e), row=(lane>>4)*4+reg (t); each
    // 16-lane group g holds exactly one chunk (4 consecutive t rows).
    const int ecol = l & 15;
    float bias[4], q1[4];
    #pragma unroll
    for (int ni = 0; ni < 4; ni++) {
        int e = e0 + we * 64 + ni * 16 + ecol;
        bias[ni] = b_proj[e];
        q1[ni]   = ln_g[e] * w_score[e];
    }
    #pragma unroll
    for (int mi = 0; mi < 4; mi++) {
        float f[4][4];
        #pragma unroll
        for (int ni = 0; ni < 4; ni++)
            #pragma unroll
            for (int r = 0; r < 4; r++)
                f[r][ni] = acc[mi][ni][r] * INV_SCALE + bias[ni];
        float red[18];
        int pi = 0;
        #pragma unroll
        for (int a2 = 0; a2 < 4; a2++)
            #pragma unroll
            for (int b2 = a2; b2 < 4; b2++) {
                float s = 0.f;
                #pragma unroll
                for (int ni = 0; ni < 4; ni++) s = fmaf(f[a2][ni], f[b2][ni], s);
                red[pi++] = s;
            }
        #pragma unroll
        for (int a2 = 0; a2 < 4; a2++) {
            float s1 = 0.f, s2 = 0.f;
            #pragma unroll
            for (int ni = 0; ni < 4; ni++) {
                s1 = fmaf(f[a2][ni], q1[ni], s1);
                s2 += f[a2][ni];
            }
            red[10 + a2] = s1;
            red[14 + a2] = s2;
        }
        #pragma unroll
        for (int v = 0; v < 18; v++) {
            float s = red[v];
            s += __shfl_xor(s, 1);
            s += __shfl_xor(s, 2);
            s += __shfl_xor(s, 4);
            s += __shfl_xor(s, 8);
            red[v] = s;
        }
        if ((l & 15) == 0) {
            int chunk = b * C_DIM + (t0 >> 2) + wm * 16 + mi * 4 + (l >> 4);
            float* dst = scal + (size_t)chunk * 18;
            #pragma unroll
            for (int v = 0; v < 18; v++) atomicAdd(dst + v, red[v]);
        }
    }
}

// ---------------------------------------------------------------------------
// Fallback fp32 GEMM (round-1 kernel, used only if ws too small)
// ---------------------------------------------------------------------------
__global__ __launch_bounds__(256, 2)
void gemm_reduce_kernel(const float* __restrict__ x, const float* __restrict__ W,
                        const float* __restrict__ b_proj, const float* __restrict__ ln_g,
                        const float* __restrict__ w_score, float* __restrict__ scal)
{
    const int tid = threadIdx.x;
    const int tx  = tid & 15;
    const int ty  = tid >> 4;
    const int t0  = blockIdx.x * 128;
    const int e0  = blockIdx.y * 128;
    const int b   = blockIdx.z;
    const float* X = x + (size_t)b * D_DIM * T_DIM;

    __shared__ __align__(16) float Xs[32][128];
    __shared__ __align__(16) float Ws[32][132];

    float acc[8][8];
    #pragma unroll
    for (int i = 0; i < 8; i++)
        #pragma unroll
        for (int j = 0; j < 8; j++) acc[i][j] = 0.f;

    for (int k0 = 0; k0 < D_DIM; k0 += 32) {
        #pragma unroll
        for (int i = 0; i < 4; i++) {
            int idx = tid + i * 256;
            int dr = idx >> 5, cl = idx & 31;
            const float4 v = *(const float4*)(X + (size_t)(k0 + dr) * T_DIM + t0 + cl * 4);
            *(float4*)&Xs[dr][cl * 4] = v;
        }
        #pragma unroll
        for (int i = 0; i < 4; i++) {
            int idx = tid + i * 256;
            int er = idx >> 3, ck = idx & 7;
            const float4 v = *(const float4*)(W + (size_t)(e0 + er) * D_DIM + k0 + ck * 4);
            Ws[ck * 4 + 0][er] = v.x;
            Ws[ck * 4 + 1][er] = v.y;
            Ws[ck * 4 + 2][er] = v.z;
            Ws[ck * 4 + 3][er] = v.w;
        }
        __syncthreads();
        #pragma unroll 8
        for (int k = 0; k < 32; k++) {
            const float4 xa = *(const float4*)&Xs[k][ty * 8];
            const float4 xb = *(const float4*)&Xs[k][ty * 8 + 4];
            const float4 wa = *(const float4*)&Ws[k][tx * 4];
            const float4 wb = *(const float4*)&Ws[k][64 + tx * 4];
            const float xm[8] = {xa.x, xa.y, xa.z, xa.w, xb.x, xb.y, xb.z, xb.w};
            const float wn[8] = {wa.x, wa.y, wa.z, wa.w, wb.x, wb.y, wb.z, wb.w};
            #pragma unroll
            for (int i = 0; i < 8; i++)
                #pragma unroll
                for (int j = 0; j < 8; j++)
                    acc[i][j] = fmaf(xm[i], wn[j], acc[i][j]);
        }
        __syncthreads();
    }

    float bv[8], q1v[8];
    #pragma unroll
    for (int j = 0; j < 8; j++) {
        int n = (j < 4) ? (tx * 4 + j) : (64 + tx * 4 + (j - 4));
        int e = e0 + n;
        bv[j]  = b_proj[e];
        q1v[j] = ln_g[e] * w_score[e];
    }
    #pragma unroll
    for (int i = 0; i < 8; i++)
        #pragma unroll
        for (int j = 0; j < 8; j++) acc[i][j] += bv[j];

    #pragma unroll
    for (int hh = 0; hh < 2; hh++) {
        float red[18];
        int p = 0;
        #pragma unroll
        for (int a = 0; a < 4; a++)
            #pragma unroll
            for (int b2 = a; b2 < 4; b2++) {
                float s = 0.f;
                #pragma unroll
                for (int j = 0; j < 8; j++) s = fmaf(acc[hh * 4 + a][j], acc[hh * 4 + b2][j], s);
                red[p++] = s;
            }
        #pragma unroll
        for (int a = 0; a < 4; a++) {
            float s1 = 0.f, s2 = 0.f;
            #pragma unroll
            for (int j = 0; j < 8; j++) {
                s1 = fmaf(acc[hh * 4 + a][j], q1v[j], s1);
                s2 += acc[hh * 4 + a][j];
            }
            red[10 + a] = s1;
            red[14 + a] = s2;
        }
        #pragma unroll
        for (int v = 0; v < 18; v++) {
            float s = red[v];
            s += __shfl_xor(s, 1);
            s += __shfl_xor(s, 2);
            s += __shfl_xor(s, 4);
            s += __shfl_xor(s, 8);
            red[v] = s;
        }
        if (tx == 0) {
            int chunk = b * C_DIM + (t0 >> 2) + ty * 2 + hh;
            float* dst = scal + (size_t)chunk * 18;
            #pragma unroll
            for (int v = 0; v < 18; v++) atomicAdd(dst + v, red[v]);
        }
    }
}

// ---------------------------------------------------------------------------
// tokN2[b][t] = sum_d x[b][d][t]^2  (fallback path only)
// ---------------------------------------------------------------------------
__global__ __launch_bounds__(256, 4)
void toknorm_kernel(const float* __restrict__ x, float* __restrict__ tokN2)
{
    const int tt = threadIdx.x & 63;
    const int ds = threadIdx.x >> 6;
    const int t  = blockIdx.x * 64 + tt;
    const int b  = blockIdx.y;
    const float* X = x + (size_t)b * D_DIM * T_DIM + t;
    float s = 0.f;
    const int d0 = ds * 256;
    for (int d = d0; d < d0 + 256; d++) {
        float v = X[(size_t)d * T_DIM];
        s = fmaf(v, v, s);
    }
    __shared__ float lred[256];
    lred[threadIdx.x] = s;
    __syncthreads();
    if (ds == 0)
        tokN2[b * T_DIM + t] = lred[tt] + lred[64 + tt] + lred[128 + tt] + lred[192 + tt];
}

// ---------------------------------------------------------------------------
// per-chunk scalars -> coef[4]
// ---------------------------------------------------------------------------
__global__ __launch_bounds__(256, 4)
void coef_kernel(const float* __restrict__ scal, const float* __restrict__ tokN2,
                 const float* __restrict__ ln_g, const float* __restrict__ ln_b,
                 const float* __restrict__ w_score, float* __restrict__ coef)
{
    const int tid = threadIdx.x;
    float p1 = 0.f, p2 = 0.f;
    for (int d = tid; d < D_DIM; d += 256) {
        float wsv = w_score[d];
        p1 = fmaf(ln_g[d], wsv, p1);
        p2 = fmaf(ln_b[d], wsv, p2);
    }
    __shared__ float r1[256], r2[256];
    r1[tid] = p1; r2[tid] = p2;
    __syncthreads();
    for (int s = 128; s > 0; s >>= 1) {
        if (tid < s) { r1[tid] += r1[tid + s]; r2[tid] += r2[tid + s]; }
        __syncthreads();
    }
    const float c1 = r1[0], c2 = r2[0];

    const int chunk = blockIdx.x * 256 + tid;
    const float* s = scal + (size_t)chunk * 18;
    float G[4][4];
    G[0][0] = s[0]; G[0][1] = s[1]; G[0][2] = s[2]; G[0][3] = s[3];
    G[1][1] = s[4]; G[1][2] = s[5]; G[1][3] = s[6];
    G[2][2] = s[7]; G[2][3] = s[8]; G[3][3] = s[9];
    G[1][0] = G[0][1]; G[2][0] = G[0][2]; G[3][0] = G[0][3];
    G[2][1] = G[1][2]; G[3][1] = G[1][3]; G[3][2] = G[2][3];

    const int b = chunk >> 10;
    const int c = chunk & 1023;

    float smix[4], nrm[4];
    #pragma unroll
    for (int i = 0; i < 4; i++) {
        float mu  = s[14 + i] * (1.f / 1024.f);
        float var = G[i][i] * (1.f / 1024.f) - mu * mu;
        float sig = sqrtf(var + LN_EPS);
        float spred = (s[10 + i] - mu * c1) / sig + c2;
        float imp = sqrtf(tokN2[b * T_DIM + c * 4 + i]);
        smix[i] = ALPHA * spred + (1.f - ALPHA) * imp;
        nrm[i]  = fmaxf(sqrtf(G[i][i]), 1e-12f);
    }
    int top = 0; float best = smix[0];
    #pragma unroll
    for (int i = 1; i < 4; i++)
        if (smix[i] > best) { best = smix[i]; top = i; }

    float sim[4][4];
    #pragma unroll
    for (int i = 0; i < 4; i++)
        #pragma unroll
        for (int j = 0; j < 4; j++)
            sim[i][j] = (i == j) ? 0.f : G[i][j] / (nrm[i] * nrm[j]);

    float cf[4];
    #pragma unroll
    for (int r = 0; r < 4; r++) {
        if (r == top) { cf[r] = 1.f; continue; }
        float z[4], m = -1e30f;
        #pragma unroll
        for (int j = 0; j < 4; j++) { z[j] = sim[r][j] * TAU_INV; m = fmaxf(m, z[j]); }
        float denom = 0.f, num = 0.f;
        #pragma unroll
        for (int j = 0; j < 4; j++) {
            float e = expf(z[j] - m);
            denom += e;
            if (j == top) num = e;
        }
        float a = num / denom;
        cf[r] = 0.5f * (a / (a + 1e-6f));
    }
    *(float4*)(coef + (size_t)chunk * 4) = make_float4(cf[0], cf[1], cf[2], cf[3]);
}

// ---------------------------------------------------------------------------
// out[b][d][c] = sum_i coef[b*C+c][i] * x[b][d][4c+i]
// ---------------------------------------------------------------------------
__global__ __launch_bounds__(256, 8)
void out_kernel(const float* __restrict__ x, const float* __restrict__ coef,
                float* __restrict__ out)
{
    const size_t gid = (size_t)blockIdx.x * 256 + threadIdx.x;
    const int    c   = (int)(gid & 1023);
    const size_t bd  = gid >> 10;
    const int    b   = (int)(bd >> 10);
    const float4 xv = *(const float4*)(x + (bd << 12) + (size_t)c * 4);
    const float4 cf = *(const float4*)(coef + ((size_t)(b << 10) + c) * 4);
    out[gid] = xv.x * cf.x + xv.y * cf.y + xv.z * cf.z + xv.w * cf.w;
}

// ---------------------------------------------------------------------------
extern "C" void kernel_launch(void* const* d_in, const int* in_sizes, int n_in,
                              void* d_out, int out_size, void* d_ws, size_t ws_size,
                              hipStream_t stream)
{
    const float* x   = (const float*)d_in[0];
    const float* W   = (const float*)d_in[1];
    const float* bp  = (const float*)d_in[2];
    const float* g   = (const float*)d_in[3];
    const float* lb  = (const float*)d_in[4];
    const float* wsc = (const float*)d_in[5];
    float* out = (float*)d_out;

    const size_t XH_BYTES = (size_t)B_DIM * NKT * TPAIR * 128;   // 128 MiB
    const size_t WH_BYTES = (size_t)NKT * EPAIR * 128;           // 2 MiB
    const size_t NEED = 2 * XH_BYTES + 2 * WH_BYTES
                      + (size_t)NCHUNK * 18 * 4 + (size_t)B_DIM * T_DIM * 4
                      + (size_t)NCHUNK * 4 * 4;

    if (ws_size >= NEED) {
        char* w0 = (char*)d_ws;
        uint4* Xh = (uint4*)w0;
        uint4* Xl = (uint4*)(w0 + XH_BYTES);
        uint4* Wh = (uint4*)(w0 + 2 * XH_BYTES);
        uint4* Wl = (uint4*)(w0 + 2 * XH_BYTES + WH_BYTES);
        float* scal  = (float*)(w0 + 2 * XH_BYTES + 2 * WH_BYTES);
        float* tokN2 = scal + (size_t)NCHUNK * 18;
        float* coef  = tokN2 + (size_t)B_DIM * T_DIM;

        // zero scal AND tokN2 (contiguous; tokN2 now accumulated by split_x)
        hipMemsetAsync(scal, 0,
                       ((size_t)NCHUNK * 18 + (size_t)B_DIM * T_DIM) * sizeof(float),
                       stream);
        split_x_kernel<<<dim3(T_DIM / 256, NKT, B_DIM), 256, 0, stream>>>(x, Xh, Xl, tokN2);
        split_w_kernel<<<dim3(D_DIM / 256, NKT), 256, 0, stream>>>(W, Wh, Wl);
        gemm_mfma_kernel<<<4096, 256, 0, stream>>>(Xh, Xl, Wh, Wl, bp, g, wsc, scal);
        coef_kernel<<<NCHUNK / 256, 256, 0, stream>>>(scal, tokN2, g, lb, wsc, coef);
        out_kernel<<<(B_DIM * D_DIM * C_DIM) / 256, 256, 0, stream>>>(x, coef, out);
    } else {
        float* scal  = (float*)d_ws;
        float* tokN2 = scal + (size_t)NCHUNK * 18;
        float* coef  = tokN2 + (size_t)B_DIM * T_DIM;

        hipMemsetAsync(scal, 0, (size_t)NCHUNK * 18 * sizeof(float), stream);
        dim3 gA(T_DIM / 128, D_DIM / 128, B_DIM);
        gemm_reduce_kernel<<<gA, 256, 0, stream>>>(x, W, bp, g, wsc, scal);
        toknorm_kernel<<<dim3(T_DIM / 64, B_DIM), 256, 0, stream>>>(x, tokN2);
        coef_kernel<<<NCHUNK / 256, 256, 0, stream>>>(scal, tokN2, g, lb, wsc, coef);
        out_kernel<<<(B_DIM * D_DIM * C_DIM) / 256, 256, 0, stream>>>(x, coef, out);
    }
}

// Round 7
// 1318.484 us; speedup vs baseline: 1.3505x; 1.3505x over previous
//
#include <hip/hip_runtime.h>
#include <hip/hip_bf16.h>
#include <math.h>
#include <stdint.h>

// Problem constants (fixed by setup_inputs)
#define D_DIM 1024
#define T_DIM 4096
#define B_DIM 16
#define C_DIM 1024              // T/RATE, RATE=4
#define NCHUNK (B_DIM * C_DIM)  // 16384
#define NKT 32                  // D/32 k-tiles
#define TPAIR (T_DIM/2)         // 2048 t-pair rows per (b,kt)
#define EPAIR (D_DIM/2)         // 512 e-pair rows per kt
#define TAU_INV 10.0f
#define ALPHA 0.7f
#define LN_EPS 1e-5f
#define XSCALE 4.0f
#define WSCALE 32.0f
#define INV_SCALE (1.0f/128.0f)

typedef _Float16 h8 __attribute__((ext_vector_type(8)));
typedef float f4 __attribute__((ext_vector_type(4)));

static __device__ __forceinline__ void gload16(const void* g, void* s) {
    __builtin_amdgcn_global_load_lds(
        (const __attribute__((address_space(1))) unsigned int*)g,
        (__attribute__((address_space(3))) unsigned int*)s, 16, 0, 0);
}

#define VMCNT0 asm volatile("s_waitcnt vmcnt(0)" ::: "memory")
#define LGKM0  asm volatile("s_waitcnt lgkmcnt(0)" ::: "memory")
#define BAR    __builtin_amdgcn_s_barrier()
#define SCHEDB __builtin_amdgcn_sched_barrier(0)

// ---------------------------------------------------------------------------
// Pre-pass X: fp32 [B][D][T] -> split-fp16 hi/lo, transposed+swizzled layout:
// element hi(x[b][d][t]*4) at row tp=t>>1 (within (b,kt)), slot
// sigma = ((t&1)*4 + (d>>3)%4) ^ (tp&7), half j = d&7. Rows are 128B; a
// GEMM A/B tile is a CONTIGUOUS region -> global_load_lds direct.
// ---------------------------------------------------------------------------
__global__ __launch_bounds__(256)
void split_x_kernel(const float* __restrict__ x, uint4* __restrict__ Xh,
                    uint4* __restrict__ Xl)
{
    const int tid = threadIdx.x;
    const int t1 = blockIdx.x * 256;
    const int kt = blockIdx.y;
    const int b  = blockIdx.z;
    const int d0 = kt * 32;
    __shared__ __align__(16) float xs[32][264];
    const float* X = x + ((size_t)b * D_DIM + d0) * T_DIM + t1;
    #pragma unroll
    for (int i = 0; i < 8; i++) {
        int idx = tid + i * 256;
        int d = idx >> 6, tq = idx & 63;
        *(float4*)&xs[d][tq * 4] = *(const float4*)(X + (size_t)d * T_DIM + tq * 4);
    }
    __syncthreads();
    const size_t rowbase = (size_t)(b * NKT + kt) * TPAIR + (t1 >> 1);
    #pragma unroll
    for (int ch = 0; ch < 4; ch++) {
        int tp_l = ch * 32 + (tid >> 3);
        int sg = tid & 7;
        int pg = sg ^ (tp_l & 7);
        int p = pg >> 2, g = pg & 3;
        int tl = tp_l * 2 + p;
        unsigned hb[8], lb[8];
        #pragma unroll
        for (int j = 0; j < 8; j++) {
            float v = xs[g * 8 + j][tl] * XSCALE;
            _Float16 hv = (_Float16)v;
            float hf = (float)hv;
            _Float16 lv = (_Float16)(v - hf);
            hb[j] = (unsigned)__builtin_bit_cast(unsigned short, hv);
            lb[j] = (unsigned)__builtin_bit_cast(unsigned short, lv);
        }
        uint4 uh, ul;
        uh.x = hb[0] | (hb[1] << 16); uh.y = hb[2] | (hb[3] << 16);
        uh.z = hb[4] | (hb[5] << 16); uh.w = hb[6] | (hb[7] << 16);
        ul.x = lb[0] | (lb[1] << 16); ul.y = lb[2] | (lb[3] << 16);
        ul.z = lb[4] | (lb[5] << 16); ul.w = lb[6] | (lb[7] << 16);
        size_t si = (rowbase + tp_l) * 8 + sg;
        Xh[si] = uh; Xl[si] = ul;
    }
}

// ---------------------------------------------------------------------------
// Pre-pass W: [e][d] fp32 -> split-fp16 hi/lo, same paired-row swizzled layout
// ---------------------------------------------------------------------------
__global__ __launch_bounds__(256)
void split_w_kernel(const float* __restrict__ W, uint4* __restrict__ Wh,
                    uint4* __restrict__ Wl)
{
    const int tid = threadIdx.x;
    const int e1 = blockIdx.x * 256;
    const int kt = blockIdx.y;
    const int d0 = kt * 32;
    const size_t rowbase = (size_t)kt * EPAIR + (e1 >> 1);
    #pragma unroll
    for (int ch = 0; ch < 4; ch++) {
        int ep_l = ch * 32 + (tid >> 3);
        int sg = tid & 7;
        int pg = sg ^ (ep_l & 7);
        int p = pg >> 2, g = pg & 3;
        int e = e1 + ep_l * 2 + p;
        const float* src = W + (size_t)e * D_DIM + d0 + g * 8;
        float4 a = *(const float4*)src;
        float4 c = *(const float4*)(src + 4);
        float vv[8] = {a.x, a.y, a.z, a.w, c.x, c.y, c.z, c.w};
        unsigned hb[8], lb[8];
        #pragma unroll
        for (int j = 0; j < 8; j++) {
            float v = vv[j] * WSCALE;
            _Float16 hv = (_Float16)v;
            float hf = (float)hv;
            _Float16 lv = (_Float16)(v - hf);
            hb[j] = (unsigned)__builtin_bit_cast(unsigned short, hv);
            lb[j] = (unsigned)__builtin_bit_cast(unsigned short, lv);
        }
        uint4 uh, ul;
        uh.x = hb[0] | (hb[1] << 16); uh.y = hb[2] | (hb[3] << 16);
        uh.z = hb[4] | (hb[5] << 16); uh.w = hb[6] | (hb[7] << 16);
        ul.x = lb[0] | (lb[1] << 16); ul.y = lb[2] | (lb[3] << 16);
        ul.z = lb[4] | (lb[5] << 16); ul.w = lb[6] | (lb[7] << 16);
        size_t si = (rowbase + ep_l) * 8 + sg;
        Wh[si] = uh; Wl[si] = ul;
    }
}

// ---------------------------------------------------------------------------
// MFMA GEMM, 256x256 tile, BK=32, 8 waves (2x4, each 128x64 out), 4-phase
// m201-style schedule: per phase {ds_read frag pair | issue 2 prefetch
// gloads -> barrier -> lgkmcnt(0) -> setprio(1) 24 MFMA setprio(0) ->
// barrier}; vmcnt(0) only at iteration top (waits only PREVIOUS iter's
// loads). LDS 2x64KB double buffer. Fused chunk-scalar epilogue.
// ---------------------------------------------------------------------------
__global__ __launch_bounds__(512, 2)
void gemm_mfma_kernel(const uint4* __restrict__ Xh, const uint4* __restrict__ Xl,
                      const uint4* __restrict__ Wh, const uint4* __restrict__ Wl,
                      const float* __restrict__ b_proj, const float* __restrict__ ln_g,
                      const float* __restrict__ w_score, float* __restrict__ scal)
{
    const int tid = threadIdx.x;
    const int l   = tid & 63;
    const int wid = tid >> 6;       // 0..7
    const int wm  = wid >> 2;       // 0..1 (t)
    const int we  = wid & 3;        // 0..3 (e)

    // XCD-chunked swizzle (1024 blocks, %8==0 -> bijective): 4 e-blocks of a
    // t-panel are adjacent ids on the same XCD.
    int sid  = blockIdx.x;
    int xcd  = sid & 7, jj = sid >> 3;     // jj in [0,128)
    int eblk = jj & 3;
    int panel = xcd * 32 + (jj >> 2);      // [0,256)
    int b = panel >> 4, tblk = panel & 15;
    const int t0 = tblk * 256, e0 = eblk * 256;

    __shared__ __align__(16) char lds[131072];   // 2 x {Ah,Al,Bh,Bl} x 16KB

    const int h    = (l & 15) >> 1;
    const int slot = (((l & 1) << 2) | (l >> 4)) ^ h;
    const int abase = (wm * 64 + h) * 128 + slot * 16;   // + mi*1024
    const int bbase = (we * 32 + h) * 128 + slot * 16;   // + ni*1024

    f4 acc[8][4];
    #pragma unroll
    for (int mi = 0; mi < 8; mi++)
        #pragma unroll
        for (int ni = 0; ni < 4; ni++) acc[mi][ni] = (f4){0.f, 0.f, 0.f, 0.f};

    const char* gXh0 = (const char*)Xh + ((size_t)b * NKT * TPAIR + (size_t)(t0 >> 1)) * 128;
    const char* gXl0 = (const char*)Xl + ((size_t)b * NKT * TPAIR + (size_t)(t0 >> 1)) * 128;
    const char* gWh0 = (const char*)Wh + (size_t)(e0 >> 1) * 128;
    const char* gWl0 = (const char*)Wl + (size_t)(e0 >> 1) * 128;

    const int sw = wid * 2048;   // this wave's 2KB slice of each 16KB comp
    const int lo = l * 16;

    auto stage1 = [&](const char* src, char* dstbase) {
        gload16(src + sw + lo,        dstbase + sw);
        gload16(src + sw + 1024 + lo, dstbase + sw + 1024);
    };
    auto trip = [&](const h8& ah_, const h8& al_, const h8& bh_, const h8& bl_, f4& c) {
        c = __builtin_amdgcn_mfma_f32_16x16x32_f16(ah_, bh_, c, 0, 0, 0);
        c = __builtin_amdgcn_mfma_f32_16x16x32_f16(ah_, bl_, c, 0, 0, 0);
        c = __builtin_amdgcn_mfma_f32_16x16x32_f16(al_, bh_, c, 0, 0, 0);
    };

    // prologue: stage kt=0 into buf0
    {
        stage1(gXh0, lds);
        stage1(gXl0, lds + 16384);
        stage1(gWh0, lds + 32768);
        stage1(gWl0, lds + 49152);
    }

    h8 bh0, bh1, bh2, bh3, bl0, bl1, bl2, bl3;
    int off = 0;
    #pragma unroll 1
    for (int kt = 0; kt < NKT; kt++) {
        VMCNT0;                      // cur tile's loads (issued LAST iter) landed
        BAR;                         // all waves agree: cur resident
        const char* cb = lds + off;
        char* nb = lds + (off ^ 65536);
        const bool st = (kt + 1 < NKT);
        const size_t k1 = (size_t)(kt + 1);
        const char* pxh = gXh0 + k1 * (TPAIR * 128);
        const char* pxl = gXl0 + k1 * (TPAIR * 128);
        const char* pwh = gWh0 + k1 * (EPAIR * 128);
        const char* pwl = gWl0 + k1 * (EPAIR * 128);

#define PHASE(p, SRC, DSTOFF)                                                   \
        {                                                                       \
            h8 a0h = *(const h8*)(cb + abase + (p) * 2048);                     \
            h8 a0l = *(const h8*)(cb + 16384 + abase + (p) * 2048);             \
            h8 a1h = *(const h8*)(cb + abase + (p) * 2048 + 1024);              \
            h8 a1l = *(const h8*)(cb + 16384 + abase + (p) * 2048 + 1024);      \
            if ((p) == 0) {                                                     \
                bh0 = *(const h8*)(cb + 32768 + bbase);                         \
                bh1 = *(const h8*)(cb + 32768 + bbase + 1024);                  \
                bh2 = *(const h8*)(cb + 32768 + bbase + 2048);                  \
                bh3 = *(const h8*)(cb + 32768 + bbase + 3072);                  \
                bl0 = *(const h8*)(cb + 49152 + bbase);                         \
                bl1 = *(const h8*)(cb + 49152 + bbase + 1024);                  \
                bl2 = *(const h8*)(cb + 49152 + bbase + 2048);                  \
                bl3 = *(const h8*)(cb + 49152 + bbase + 3072);                  \
            }                                                                   \
            if (st) stage1(SRC, nb + DSTOFF);                                   \
            BAR;                                                                \
            LGKM0; SCHEDB;                                                      \
            __builtin_amdgcn_s_setprio(1);                                      \
            trip(a0h, a0l, bh0, bl0, acc[2*(p)][0]);                            \
            trip(a0h, a0l, bh1, bl1, acc[2*(p)][1]);                            \
            trip(a0h, a0l, bh2, bl2, acc[2*(p)][2]);                            \
            trip(a0h, a0l, bh3, bl3, acc[2*(p)][3]);                            \
            trip(a1h, a1l, bh0, bl0, acc[2*(p)+1][0]);                          \
            trip(a1h, a1l, bh1, bl1, acc[2*(p)+1][1]);                          \
            trip(a1h, a1l, bh2, bl2, acc[2*(p)+1][2]);                          \
            trip(a1h, a1l, bh3, bl3, acc[2*(p)+1][3]);                          \
            __builtin_amdgcn_s_setprio(0);                                      \
            BAR;                                                                \
        }

        PHASE(0, pxh, 0)
        PHASE(1, pxl, 16384)
        PHASE(2, pwh, 32768)
        PHASE(3, pwl, 49152)
#undef PHASE
        off ^= 65536;
    }

    // Epilogue: C/D layout col=lane&15 (e), row=(lane>>4)*4+reg (t); each
    // 16-lane group holds one chunk (4 consecutive t rows) per mi block.
    const int ecol = l & 15;
    float bias[4], q1[4];
    #pragma unroll
    for (int ni = 0; ni < 4; ni++) {
        int e = e0 + we * 64 + ni * 16 + ecol;
        bias[ni] = b_proj[e];
        q1[ni]   = ln_g[e] * w_score[e];
    }
    #pragma unroll
    for (int mi = 0; mi < 8; mi++) {
        float f[4][4];
        #pragma unroll
        for (int ni = 0; ni < 4; ni++)
            #pragma unroll
            for (int r = 0; r < 4; r++)
                f[r][ni] = acc[mi][ni][r] * INV_SCALE + bias[ni];
        float red[18];
        int pi = 0;
        #pragma unroll
        for (int a2 = 0; a2 < 4; a2++)
            #pragma unroll
            for (int b2 = a2; b2 < 4; b2++) {
                float s = 0.f;
                #pragma unroll
                for (int ni = 0; ni < 4; ni++) s = fmaf(f[a2][ni], f[b2][ni], s);
                red[pi++] = s;
            }
        #pragma unroll
        for (int a2 = 0; a2 < 4; a2++) {
            float s1 = 0.f, s2 = 0.f;
            #pragma unroll
            for (int ni = 0; ni < 4; ni++) {
                s1 = fmaf(f[a2][ni], q1[ni], s1);
                s2 += f[a2][ni];
            }
            red[10 + a2] = s1;
            red[14 + a2] = s2;
        }
        #pragma unroll
        for (int v = 0; v < 18; v++) {
            float s = red[v];
            s += __shfl_xor(s, 1);
            s += __shfl_xor(s, 2);
            s += __shfl_xor(s, 4);
            s += __shfl_xor(s, 8);
            red[v] = s;
        }
        if ((l & 15) == 0) {
            int chunk = b * C_DIM + ((t0 + wm * 128 + mi * 16) >> 2) + (l >> 4);
            float* dst = scal + (size_t)chunk * 18;
            #pragma unroll
            for (int v = 0; v < 18; v++) atomicAdd(dst + v, red[v]);
        }
    }
}

// ---------------------------------------------------------------------------
// Fallback fp32 GEMM (round-1 kernel, used only if ws too small)
// ---------------------------------------------------------------------------
__global__ __launch_bounds__(256, 2)
void gemm_reduce_kernel(const float* __restrict__ x, const float* __restrict__ W,
                        const float* __restrict__ b_proj, const float* __restrict__ ln_g,
                        const float* __restrict__ w_score, float* __restrict__ scal)
{
    const int tid = threadIdx.x;
    const int tx  = tid & 15;
    const int ty  = tid >> 4;
    const int t0  = blockIdx.x * 128;
    const int e0  = blockIdx.y * 128;
    const int b   = blockIdx.z;
    const float* X = x + (size_t)b * D_DIM * T_DIM;

    __shared__ __align__(16) float Xs[32][128];
    __shared__ __align__(16) float Ws[32][132];

    float acc[8][8];
    #pragma unroll
    for (int i = 0; i < 8; i++)
        #pragma unroll
        for (int j = 0; j < 8; j++) acc[i][j] = 0.f;

    for (int k0 = 0; k0 < D_DIM; k0 += 32) {
        #pragma unroll
        for (int i = 0; i < 4; i++) {
            int idx = tid + i * 256;
            int dr = idx >> 5, cl = idx & 31;
            const float4 v = *(const float4*)(X + (size_t)(k0 + dr) * T_DIM + t0 + cl * 4);
            *(float4*)&Xs[dr][cl * 4] = v;
        }
        #pragma unroll
        for (int i = 0; i < 4; i++) {
            int idx = tid + i * 256;
            int er = idx >> 3, ck = idx & 7;
            const float4 v = *(const float4*)(W + (size_t)(e0 + er) * D_DIM + k0 + ck * 4);
            Ws[ck * 4 + 0][er] = v.x;
            Ws[ck * 4 + 1][er] = v.y;
            Ws[ck * 4 + 2][er] = v.z;
            Ws[ck * 4 + 3][er] = v.w;
        }
        __syncthreads();
        #pragma unroll 8
        for (int k = 0; k < 32; k++) {
            const float4 xa = *(const float4*)&Xs[k][ty * 8];
            const float4 xb = *(const float4*)&Xs[k][ty * 8 + 4];
            const float4 wa = *(const float4*)&Ws[k][tx * 4];
            const float4 wb = *(const float4*)&Ws[k][64 + tx * 4];
            const float xm[8] = {xa.x, xa.y, xa.z, xa.w, xb.x, xb.y, xb.z, xb.w};
            const float wn[8] = {wa.x, wa.y, wa.z, wa.w, wb.x, wb.y, wb.z, wb.w};
            #pragma unroll
            for (int i = 0; i < 8; i++)
                #pragma unroll
                for (int j = 0; j < 8; j++)
                    acc[i][j] = fmaf(xm[i], wn[j], acc[i][j]);
        }
        __syncthreads();
    }

    float bv[8], q1v[8];
    #pragma unroll
    for (int j = 0; j < 8; j++) {
        int n = (j < 4) ? (tx * 4 + j) : (64 + tx * 4 + (j - 4));
        int e = e0 + n;
        bv[j]  = b_proj[e];
        q1v[j] = ln_g[e] * w_score[e];
    }
    #pragma unroll
    for (int i = 0; i < 8; i++)
        #pragma unroll
        for (int j = 0; j < 8; j++) acc[i][j] += bv[j];

    #pragma unroll
    for (int hh = 0; hh < 2; hh++) {
        float red[18];
        int p = 0;
        #pragma unroll
        for (int a = 0; a < 4; a++)
            #pragma unroll
            for (int b2 = a; b2 < 4; b2++) {
                float s = 0.f;
                #pragma unroll
                for (int j = 0; j < 8; j++) s = fmaf(acc[hh * 4 + a][j], acc[hh * 4 + b2][j], s);
                red[p++] = s;
            }
        #pragma unroll
        for (int a = 0; a < 4; a++) {
            float s1 = 0.f, s2 = 0.f;
            #pragma unroll
            for (int j = 0; j < 8; j++) {
                s1 = fmaf(acc[hh * 4 + a][j], q1v[j], s1);
                s2 += acc[hh * 4 + a][j];
            }
            red[10 + a] = s1;
            red[14 + a] = s2;
        }
        #pragma unroll
        for (int v = 0; v < 18; v++) {
            float s = red[v];
            s += __shfl_xor(s, 1);
            s += __shfl_xor(s, 2);
            s += __shfl_xor(s, 4);
            s += __shfl_xor(s, 8);
            red[v] = s;
        }
        if (tx == 0) {
            int chunk = b * C_DIM + (t0 >> 2) + ty * 2 + hh;
            float* dst = scal + (size_t)chunk * 18;
            #pragma unroll
            for (int v = 0; v < 18; v++) atomicAdd(dst + v, red[v]);
        }
    }
}

// ---------------------------------------------------------------------------
// tokN2[b][t] = sum_d x[b][d][t]^2
// ---------------------------------------------------------------------------
__global__ __launch_bounds__(256, 4)
void toknorm_kernel(const float* __restrict__ x, float* __restrict__ tokN2)
{
    const int tt = threadIdx.x & 63;
    const int ds = threadIdx.x >> 6;
    const int t  = blockIdx.x * 64 + tt;
    const int b  = blockIdx.y;
    const float* X = x + (size_t)b * D_DIM * T_DIM + t;
    float s = 0.f;
    const int d0 = ds * 256;
    for (int d = d0; d < d0 + 256; d++) {
        float v = X[(size_t)d * T_DIM];
        s = fmaf(v, v, s);
    }
    __shared__ float lred[256];
    lred[threadIdx.x] = s;
    __syncthreads();
    if (ds == 0)
        tokN2[b * T_DIM + t] = lred[tt] + lred[64 + tt] + lred[128 + tt] + lred[192 + tt];
}

// ---------------------------------------------------------------------------
// per-chunk scalars -> coef[4]
// ---------------------------------------------------------------------------
__global__ __launch_bounds__(256, 4)
void coef_kernel(const float* __restrict__ scal, const float* __restrict__ tokN2,
                 const float* __restrict__ ln_g, const float* __restrict__ ln_b,
                 const float* __restrict__ w_score, float* __restrict__ coef)
{
    const int tid = threadIdx.x;
    float p1 = 0.f, p2 = 0.f;
    for (int d = tid; d < D_DIM; d += 256) {
        float wsv = w_score[d];
        p1 = fmaf(ln_g[d], wsv, p1);
        p2 = fmaf(ln_b[d], wsv, p2);
    }
    __shared__ float r1[256], r2[256];
    r1[tid] = p1; r2[tid] = p2;
    __syncthreads();
    for (int s = 128; s > 0; s >>= 1) {
        if (tid < s) { r1[tid] += r1[tid + s]; r2[tid] += r2[tid + s]; }
        __syncthreads();
    }
    const float c1 = r1[0], c2 = r2[0];

    const int chunk = blockIdx.x * 256 + tid;
    const float* s = scal + (size_t)chunk * 18;
    float G[4][4];
    G[0][0] = s[0]; G[0][1] = s[1]; G[0][2] = s[2]; G[0][3] = s[3];
    G[1][1] = s[4]; G[1][2] = s[5]; G[1][3] = s[6];
    G[2][2] = s[7]; G[2][3] = s[8]; G[3][3] = s[9];
    G[1][0] = G[0][1]; G[2][0] = G[0][2]; G[3][0] = G[0][3];
    G[2][1] = G[1][2]; G[3][1] = G[1][3]; G[3][2] = G[2][3];

    const int b = chunk >> 10;
    const int c = chunk & 1023;

    float smix[4], nrm[4];
    #pragma unroll
    for (int i = 0; i < 4; i++) {
        float mu  = s[14 + i] * (1.f / 1024.f);
        float var = G[i][i] * (1.f / 1024.f) - mu * mu;
        float sig = sqrtf(var + LN_EPS);
        float spred = (s[10 + i] - mu * c1) / sig + c2;
        float imp = sqrtf(tokN2[b * T_DIM + c * 4 + i]);
        smix[i] = ALPHA * spred + (1.f - ALPHA) * imp;
        nrm[i]  = fmaxf(sqrtf(G[i][i]), 1e-12f);
    }
    int top = 0; float best = smix[0];
    #pragma unroll
    for (int i = 1; i < 4; i++)
        if (smix[i] > best) { best = smix[i]; top = i; }

    float sim[4][4];
    #pragma unroll
    for (int i = 0; i < 4; i++)
        #pragma unroll
        for (int j = 0; j < 4; j++)
            sim[i][j] = (i == j) ? 0.f : G[i][j] / (nrm[i] * nrm[j]);

    float cf[4];
    #pragma unroll
    for (int r = 0; r < 4; r++) {
        if (r == top) { cf[r] = 1.f; continue; }
        float z[4], m = -1e30f;
        #pragma unroll
        for (int j = 0; j < 4; j++) { z[j] = sim[r][j] * TAU_INV; m = fmaxf(m, z[j]); }
        float denom = 0.f, num = 0.f;
        #pragma unroll
        for (int j = 0; j < 4; j++) {
            float e = expf(z[j] - m);
            denom += e;
            if (j == top) num = e;
        }
        float a = num / denom;
        cf[r] = 0.5f * (a / (a + 1e-6f));
    }
    *(float4*)(coef + (size_t)chunk * 4) = make_float4(cf[0], cf[1], cf[2], cf[3]);
}

// ---------------------------------------------------------------------------
// out[b][d][c] = sum_i coef[b*C+c][i] * x[b][d][4c+i]
// ---------------------------------------------------------------------------
__global__ __launch_bounds__(256, 8)
void out_kernel(const float* __restrict__ x, const float* __restrict__ coef,
                float* __restrict__ out)
{
    const size_t gid = (size_t)blockIdx.x * 256 + threadIdx.x;
    const int    c   = (int)(gid & 1023);
    const size_t bd  = gid >> 10;
    const int    b   = (int)(bd >> 10);
    const float4 xv = *(const float4*)(x + (bd << 12) + (size_t)c * 4);
    const float4 cf = *(const float4*)(coef + ((size_t)(b << 10) + c) * 4);
    out[gid] = xv.x * cf.x + xv.y * cf.y + xv.z * cf.z + xv.w * cf.w;
}

// ---------------------------------------------------------------------------
extern "C" void kernel_launch(void* const* d_in, const int* in_sizes, int n_in,
                              void* d_out, int out_size, void* d_ws, size_t ws_size,
                              hipStream_t stream)
{
    const float* x   = (const float*)d_in[0];
    const float* W   = (const float*)d_in[1];
    const float* bp  = (const float*)d_in[2];
    const float* g   = (const float*)d_in[3];
    const float* lb  = (const float*)d_in[4];
    const float* wsc = (const float*)d_in[5];
    float* out = (float*)d_out;

    const size_t XH_BYTES = (size_t)B_DIM * NKT * TPAIR * 128;   // 128 MiB
    const size_t WH_BYTES = (size_t)NKT * EPAIR * 128;           // 2 MiB
    const size_t NEED = 2 * XH_BYTES + 2 * WH_BYTES
                      + (size_t)NCHUNK * 18 * 4 + (size_t)B_DIM * T_DIM * 4
                      + (size_t)NCHUNK * 4 * 4;

    if (ws_size >= NEED) {
        char* w0 = (char*)d_ws;
        uint4* Xh = (uint4*)w0;
        uint4* Xl = (uint4*)(w0 + XH_BYTES);
        uint4* Wh = (uint4*)(w0 + 2 * XH_BYTES);
        uint4* Wl = (uint4*)(w0 + 2 * XH_BYTES + WH_BYTES);
        float* scal  = (float*)(w0 + 2 * XH_BYTES + 2 * WH_BYTES);
        float* tokN2 = scal + (size_t)NCHUNK * 18;
        float* coef  = tokN2 + (size_t)B_DIM * T_DIM;

        hipMemsetAsync(scal, 0, (size_t)NCHUNK * 18 * sizeof(float), stream);
        split_x_kernel<<<dim3(T_DIM / 256, NKT, B_DIM), 256, 0, stream>>>(x, Xh, Xl);
        split_w_kernel<<<dim3(D_DIM / 256, NKT), 256, 0, stream>>>(W, Wh, Wl);
        toknorm_kernel<<<dim3(T_DIM / 64, B_DIM), 256, 0, stream>>>(x, tokN2);
        gemm_mfma_kernel<<<1024, 512, 0, stream>>>(Xh, Xl, Wh, Wl, bp, g, wsc, scal);
        coef_kernel<<<NCHUNK / 256, 256, 0, stream>>>(scal, tokN2, g, lb, wsc, coef);
        out_kernel<<<(B_DIM * D_DIM * C_DIM) / 256, 256, 0, stream>>>(x, coef, out);
    } else {
        float* scal  = (float*)d_ws;
        float* tokN2 = scal + (size_t)NCHUNK * 18;
        float* coef  = tokN2 + (size_t)B_DIM * T_DIM;

        hipMemsetAsync(scal, 0, (size_t)NCHUNK * 18 * sizeof(float), stream);
        dim3 gA(T_DIM / 128, D_DIM / 128, B_DIM);
        gemm_reduce_kernel<<<gA, 256, 0, stream>>>(x, W, bp, g, wsc, scal);
        toknorm_kernel<<<dim3(T_DIM / 64, B_DIM), 256, 0, stream>>>(x, tokN2);
        coef_kernel<<<NCHUNK / 256, 256, 0, stream>>>(scal, tokN2, g, lb, wsc, coef);
        out_kernel<<<(B_DIM * D_DIM * C_DIM) / 256, 256, 0, stream>>>(x, coef, out);
    }
}